// Round 4
// baseline (223.588 us; speedup 1.0000x reference)
//
#include <hip/hip_runtime.h>
#include <math.h>

#define BATCH 256
#define FB    64
#define NCOL  147456   // 128*128*3*3
#define TPB   256
#define NB    64       // n-cols per block
#define PAD   72       // LDS row pitch (u16): 16B-aligned rows, 2-way (free) b128 conflicts

typedef short short8 __attribute__((ext_vector_type(8)));   // 8 bf16 = 4 VGPRs (MFMA A/B frag)
typedef float f32x4  __attribute__((ext_vector_type(4)));   // MFMA C/D frag

static __device__ __forceinline__ unsigned short f2bf(float x) {
    unsigned int u = __float_as_uint(x);
    unsigned int r = (u + 0x7FFF + ((u >> 16) & 1)) >> 16;  // RNE
    return (unsigned short)r;
}

// One wave per batch row; emits bf16 probs row-major [b][64] — this is exactly
// the MFMA A-operand feed (lane&15 = b, 8 consecutive f per lane = 16B load).
__global__ void softmax_bf16(const float* __restrict__ x, unsigned short* __restrict__ p) {
    const int b = blockIdx.x;
    const int lane = threadIdx.x;   // == filter f
    float v = x[b * FB + lane];
    float m = v;
#pragma unroll
    for (int o = 32; o > 0; o >>= 1) m = fmaxf(m, __shfl_xor(m, o));
    float e = __expf(v - m);
    float s = e;
#pragma unroll
    for (int o = 32; o > 0; o >>= 1) s += __shfl_xor(s, o);
    p[b * FB + lane] = f2bf(e / s);
}

// out[b][n] = sum_f P[b][f] * W[f][n]   via mfma_f32_16x16x32_bf16
// Block: 256 thr = 4 waves, 64 n-cols, all 256 batches. Grid: NCOL/64 = 2304.
// W tile staged fp32->bf16 TRANSPOSED in LDS (Wt[n][f]) so B-fragments are
// contiguous ds_read_b128; loaded once per wave, reused across 16 b-tiles.
__global__ __launch_bounds__(TPB) void bank_gemm_mfma(
        const float* __restrict__ W, const unsigned short* __restrict__ P,
        float* __restrict__ out) {
    __shared__ __align__(16) unsigned short Wt[NB * PAD];

    const int tid = threadIdx.x;
    const int n0  = blockIdx.x * NB;

    // ---- Stage W[0..63][n0..n0+63] -> Wt[n][f] (bf16), pair-packed b32 writes.
    const float* __restrict__ Wp = W + n0;
#pragma unroll
    for (int i = 0; i < 8; ++i) {
        const int e2 = i * 256 + tid;      // 2048 f-pairs
        const int f2 = e2 >> 6;            // 0..31 (f = 2*f2)
        const int n  = e2 & 63;            // consecutive lanes -> consecutive n (coalesced)
        const float a = Wp[(2 * f2)     * NCOL + n];
        const float b = Wp[(2 * f2 + 1) * NCOL + n];
        const unsigned int pk = (unsigned int)f2bf(a) | ((unsigned int)f2bf(b) << 16);
        *(unsigned int*)&Wt[n * PAD + 2 * f2] = pk;
    }
    __syncthreads();

    const int l  = tid & 63;
    const int w  = tid >> 6;
    const int nq = l & 15;          // MFMA row/col lane index
    const int q  = l >> 4;          // k-chunk quad (0..3)
    const int nw = w * 16 + nq;     // this lane's n within block

    // B-fragments: load ONCE, reuse across all 16 batch-tiles.
    const short8 b0 = *(const short8*)&Wt[nw * PAD + q * 8];        // f = q*8 + 0..7
    const short8 b1 = *(const short8*)&Wt[nw * PAD + 32 + q * 8];   // f = 32 + q*8 + 0..7

    const int ncol_n = n0 + nw;
    float* __restrict__ ob = out + ncol_n;

#pragma unroll 4
    for (int bt = 0; bt < BATCH / 16; ++bt) {
        // A-fragments: probs bf16 row-major, lane = (b = bt*16+nq, f-chunk q)
        const int off = (bt * 16 + nq) * FB + q * 8;
        const short8 a0 = *(const short8*)(P + off);
        const short8 a1 = *(const short8*)(P + off + 32);

        f32x4 d = {0.f, 0.f, 0.f, 0.f};
        d = __builtin_amdgcn_mfma_f32_16x16x32_bf16(a0, b0, d, 0, 0, 0);
        d = __builtin_amdgcn_mfma_f32_16x16x32_bf16(a1, b1, d, 0, 0, 0);

        // D: col = lane&15 = n (coalesced 64B segments), row = q*4 + r = b
        const int bb = bt * 16 + q * 4;
#pragma unroll
        for (int r = 0; r < 4; ++r) {
            __builtin_nontemporal_store(d[r], ob + (long long)(bb + r) * NCOL);
        }
    }
}

extern "C" void kernel_launch(void* const* d_in, const int* in_sizes, int n_in,
                              void* d_out, int out_size, void* d_ws, size_t ws_size,
                              hipStream_t stream) {
    const float* bank   = (const float*)d_in[0];   // (256, 64)
    const float* weight = (const float*)d_in[1];   // (64, 128,128,3,3)
    float* out = (float*)d_out;                    // (256, 147456) fp32
    unsigned short* probs = (unsigned short*)d_ws; // 256*64 bf16 = 32 KB scratch

    softmax_bf16<<<BATCH, FB, 0, stream>>>(bank, probs);
    bank_gemm_mfma<<<NCOL / NB, TPB, 0, stream>>>(weight, probs, out);
}